// Round 1
// baseline (379.701 us; speedup 1.0000x reference)
//
#include <hip/hip_runtime.h>
#include <stdint.h>

typedef unsigned long long u64;

#define NCLS 20
#define NBUCK 400
#define LSTR (NBUCK + 1)          // padded LDS stride (u64 units)
#define CNT_SHIFT 44
#define SUM_MASK ((1ull << CNT_SHIFT) - 1ull)
#define FPSCALE 16777216.0f       // 2^24 fixed-point scale for err sums

// Histogram kernel: fused softmax + |onehot - prob| bucketing.
// Negatives (19/20 of elements) -> LDS histogram (u64 packed cnt|sum),
// flushed once per block via global u64 atomics.
// Positives (1 per row) -> direct global u64 atomics.
__global__ __launch_bounds__(512, 2) void lovasz_hist(
    const float* __restrict__ x, const int* __restrict__ tgt,
    u64* __restrict__ gN, u64* __restrict__ gP, int n)
{
    __shared__ u64 sN[NCLS * LSTR];          // 20*401*8 = 64160 B
    for (int i = threadIdx.x; i < NCLS * LSTR; i += blockDim.x) sN[i] = 0;
    __syncthreads();

    const int stride = gridDim.x * blockDim.x;
    for (int row = blockIdx.x * blockDim.x + threadIdx.x; row < n; row += stride) {
        const float4* rp = reinterpret_cast<const float4*>(x + (size_t)row * NCLS);
        float4 q0 = rp[0], q1 = rp[1], q2 = rp[2], q3 = rp[3], q4 = rp[4];
        float v[NCLS] = {q0.x, q0.y, q0.z, q0.w,
                         q1.x, q1.y, q1.z, q1.w,
                         q2.x, q2.y, q2.z, q2.w,
                         q3.x, q3.y, q3.z, q3.w,
                         q4.x, q4.y, q4.z, q4.w};
        float m = v[0];
#pragma unroll
        for (int c = 1; c < NCLS; c++) m = fmaxf(m, v[c]);
        float s = 0.0f;
#pragma unroll
        for (int c = 0; c < NCLS; c++) s += __expf(v[c] - m);
        float inv = 1.0f / s;
        int t = tgt[row];
#pragma unroll
        for (int c = 0; c < NCLS; c++) {
            float p = __expf(v[c] - m) * inv;
            bool pos = (c == t);
            float err = fabsf(pos ? 1.0f - p : p);   // matches jnp.abs(tgt - prob)
            int b = (int)(err * (float)NBUCK);
            if (b > NBUCK - 1) b = NBUCK - 1;
            u64 pv = (1ull << CNT_SHIFT) | (u64)(err * FPSCALE);
            if (pos) atomicAdd(&gP[c * NBUCK + b], pv);
            else     atomicAdd(&sN[c * LSTR + b], pv);
        }
    }
    __syncthreads();
    // flush LDS negatives histogram to global
    for (int i = threadIdx.x; i < NCLS * NBUCK; i += blockDim.x) {
        int c = i / NBUCK;
        int b = i - c * NBUCK;
        u64 val = sN[c * LSTR + b];
        if (val) atomicAdd(&gN[i], val);
    }
}

// Final pass: per class, walk buckets in descending-error order.
// Within a bucket: positives first (all share weight 1/(P+n)), then the
// negative run, whose Lovasz weights telescope:
//   sum_k (P-p)/((P+n+k-1)(P+n+k)) = (P-p) * [1/(P+n) - 1/(P+n+K)]
__global__ void lovasz_final(const u64* __restrict__ gN, const u64* __restrict__ gP,
                             float* __restrict__ out)
{
    __shared__ double acc[NCLS];
    int c = threadIdx.x;
    if (c < NCLS) {
        double P = 0.0;
        for (int b = 0; b < NBUCK; b++)
            P += (double)(gP[c * NBUCK + b] >> CNT_SHIFT);
        double loss = 0.0, nneg = 0.0, ppos = 0.0, topAvg = -1.0;
        for (int b = NBUCK - 1; b >= 0; b--) {
            u64 vp = gP[c * NBUCK + b];
            double cp = (double)(vp >> CNT_SHIFT);
            if (cp > 0.0) {
                double sp = (double)(vp & SUM_MASK) * (1.0 / 16777216.0);
                loss += sp / (P + nneg);       // each positive: weight 1/(P+n)
                ppos += cp;
            }
            u64 vn = gN[c * NBUCK + b];
            double cn = (double)(vn >> CNT_SHIFT);
            if (cn > 0.0) {
                double sn = (double)(vn & SUM_MASK) * (1.0 / 16777216.0);
                double avg = sn / cn;
                if (topAvg < 0.0) topAvg = avg;
                double rem = P - ppos;
                if (rem > 0.0)
                    loss += avg * rem * (1.0 / (P + nneg) - 1.0 / (P + nneg + cn));
                nneg += cn;
            }
        }
        if (P == 0.0) loss = (topAvg >= 0.0) ? topAvg : 0.0;  // degenerate: loss = max err
        acc[c] = loss;
    }
    __syncthreads();
    if (threadIdx.x == 0) {
        double tsum = 0.0;
        for (int i = 0; i < NCLS; i++) tsum += acc[i];
        out[0] = (float)(tsum / (double)NCLS);
    }
}

extern "C" void kernel_launch(void* const* d_in, const int* in_sizes, int n_in,
                              void* d_out, int out_size, void* d_ws, size_t ws_size,
                              hipStream_t stream) {
    const float* x = (const float*)d_in[0];
    const int* tgt = (const int*)d_in[1];
    int n = in_sizes[0] / NCLS;

    u64* gP = (u64*)d_ws;                 // [NCLS][NBUCK] positives
    u64* gN = gP + NCLS * NBUCK;          // [NCLS][NBUCK] negatives
    hipMemsetAsync(d_ws, 0, 2ull * NCLS * NBUCK * sizeof(u64), stream);

    hipLaunchKernelGGL(lovasz_hist, dim3(512), dim3(512), 0, stream,
                       x, tgt, gN, gP, n);
    hipLaunchKernelGGL(lovasz_final, dim3(1), dim3(64), 0, stream,
                       gN, gP, (float*)d_out);
}

// Round 2
// 154.383 us; speedup vs baseline: 2.4595x; 2.4595x over previous
//
#include <hip/hip_runtime.h>
#include <stdint.h>

typedef unsigned long long u64;

#define NCLS 20
#define NBUCK 256
#define CNT_SHIFT 44
#define SUM_MASK ((1ull << CNT_SHIFT) - 1ull)

__device__ __forceinline__ unsigned short quant16(float err) {
    float f = err * 65535.0f + 0.5f;
    unsigned q = (unsigned)f;
    return (unsigned short)(q > 65534u ? 65534u : q);  // 0xFFFF reserved as sentinel
}

// ---------------- Pass 1: softmax + quantized-error transpose ----------------
// Writes negT[c][row] = err16 (0xFFFF sentinel at target slot), posE[row] = err16.
__global__ __launch_bounds__(512) void lv_pass1(
    const float* __restrict__ x, const int* __restrict__ tgt,
    unsigned short* __restrict__ negT, unsigned short* __restrict__ posE, int n)
{
    const int stride = gridDim.x * blockDim.x;
    for (int row = blockIdx.x * blockDim.x + threadIdx.x; row < n; row += stride) {
        const float4* rp = reinterpret_cast<const float4*>(x + (size_t)row * NCLS);
        float4 q0 = rp[0], q1 = rp[1], q2 = rp[2], q3 = rp[3], q4 = rp[4];
        float v[NCLS] = {q0.x,q0.y,q0.z,q0.w, q1.x,q1.y,q1.z,q1.w,
                         q2.x,q2.y,q2.z,q2.w, q3.x,q3.y,q3.z,q3.w,
                         q4.x,q4.y,q4.z,q4.w};
        float m = v[0];
#pragma unroll
        for (int c = 1; c < NCLS; c++) m = fmaxf(m, v[c]);
        float e[NCLS];
        float s = 0.0f;
#pragma unroll
        for (int c = 0; c < NCLS; c++) { e[c] = __expf(v[c] - m); s += e[c]; }
        float inv = 1.0f / s;
        int t = tgt[row];
        unsigned short pq = 0;
#pragma unroll
        for (int c = 0; c < NCLS; c++) {
            float p = e[c] * inv;
            bool pos = (c == t);
            unsigned short q = quant16(pos ? (1.0f - p) : p);
            if (pos) pq = q;
            negT[(size_t)c * n + row] = pos ? (unsigned short)0xFFFFu : q;
        }
        posE[row] = pq;
    }
}

// ---------------- Pass 2a: negatives histogram (one class per blockIdx.y) ---
// Wave-private u64 histograms: zero divergence, zero cross-wave contention.
__global__ __launch_bounds__(512) void lv_hist_neg(
    const unsigned short* __restrict__ negT, u64* __restrict__ gN, int n)
{
    __shared__ u64 sH[8][NBUCK];   // 8 waves x 2KB = 16KB
    for (int i = threadIdx.x; i < 8 * NBUCK; i += blockDim.x) ((u64*)sH)[i] = 0;
    __syncthreads();

    const int wave = threadIdx.x >> 6;
    const int c = blockIdx.y;
    const uint4* base = reinterpret_cast<const uint4*>(negT + (size_t)c * n);
    const int nv = n >> 3;                       // n divisible by 8
    const int stride = gridDim.x * blockDim.x;
    for (int i = blockIdx.x * blockDim.x + threadIdx.x; i < nv; i += stride) {
        uint4 w = base[i];
        unsigned vals[8] = {w.x & 0xFFFFu, w.x >> 16, w.y & 0xFFFFu, w.y >> 16,
                            w.z & 0xFFFFu, w.z >> 16, w.w & 0xFFFFu, w.w >> 16};
#pragma unroll
        for (int k = 0; k < 8; k++) {
            unsigned vv = vals[k];
            if (vv != 0xFFFFu)
                atomicAdd(&sH[wave][vv >> 8], (1ull << CNT_SHIFT) | (u64)vv);
        }
    }
    __syncthreads();
    for (int b = threadIdx.x; b < NBUCK; b += blockDim.x) {
        u64 t = 0;
#pragma unroll
        for (int w2 = 0; w2 < 8; w2++) t += sH[w2][b];
        if (t) atomicAdd(&gN[c * NBUCK + b], t);
    }
}

// ---------------- Pass 2b: positives histogram --------------------------------
__global__ __launch_bounds__(512) void lv_hist_pos(
    const unsigned short* __restrict__ posE, const int* __restrict__ tgt,
    u64* __restrict__ gP, int n)
{
    __shared__ u64 sH[NCLS * NBUCK];             // 40KB
    for (int i = threadIdx.x; i < NCLS * NBUCK; i += blockDim.x) sH[i] = 0;
    __syncthreads();
    const int stride = gridDim.x * blockDim.x;
    for (int i = blockIdx.x * blockDim.x + threadIdx.x; i < n; i += stride) {
        unsigned vv = posE[i];
        int t = tgt[i];
        atomicAdd(&sH[t * NBUCK + (vv >> 8)], (1ull << CNT_SHIFT) | (u64)vv);
    }
    __syncthreads();
    for (int i = threadIdx.x; i < NCLS * NBUCK; i += blockDim.x) {
        u64 v = sH[i];
        if (v) atomicAdd(&gP[i], v);
    }
}

// ---------------- Fallback (round-1 style, small ws): fused hist -------------
__global__ __launch_bounds__(512, 2) void lv_hist_fused(
    const float* __restrict__ x, const int* __restrict__ tgt,
    u64* __restrict__ gN, u64* __restrict__ gP, int n)
{
    __shared__ u64 sN[NCLS * (NBUCK + 1)];
    for (int i = threadIdx.x; i < NCLS * (NBUCK + 1); i += blockDim.x) sN[i] = 0;
    __syncthreads();
    const int stride = gridDim.x * blockDim.x;
    for (int row = blockIdx.x * blockDim.x + threadIdx.x; row < n; row += stride) {
        const float4* rp = reinterpret_cast<const float4*>(x + (size_t)row * NCLS);
        float4 q0 = rp[0], q1 = rp[1], q2 = rp[2], q3 = rp[3], q4 = rp[4];
        float v[NCLS] = {q0.x,q0.y,q0.z,q0.w, q1.x,q1.y,q1.z,q1.w,
                         q2.x,q2.y,q2.z,q2.w, q3.x,q3.y,q3.z,q3.w,
                         q4.x,q4.y,q4.z,q4.w};
        float m = v[0];
#pragma unroll
        for (int c = 1; c < NCLS; c++) m = fmaxf(m, v[c]);
        float e[NCLS]; float s = 0.0f;
#pragma unroll
        for (int c = 0; c < NCLS; c++) { e[c] = __expf(v[c] - m); s += e[c]; }
        float inv = 1.0f / s;
        int t = tgt[row];
#pragma unroll
        for (int c = 0; c < NCLS; c++) {
            float p = e[c] * inv;
            bool pos = (c == t);
            unsigned vv = quant16(pos ? (1.0f - p) : p);
            u64 pv = (1ull << CNT_SHIFT) | (u64)vv;
            if (pos) atomicAdd(&gP[c * NBUCK + (vv >> 8)], pv);
            else     atomicAdd(&sN[c * (NBUCK + 1) + (vv >> 8)], pv);
        }
    }
    __syncthreads();
    for (int i = threadIdx.x; i < NCLS * NBUCK; i += blockDim.x) {
        int c = i / NBUCK, b = i - c * NBUCK;
        u64 val = sN[c * (NBUCK + 1) + b];
        if (val) atomicAdd(&gN[i], val);
    }
}

// ---------------- Final: telescoped Lovasz walk ------------------------------
__global__ void lovasz_final(const u64* __restrict__ gN, const u64* __restrict__ gP,
                             float* __restrict__ out)
{
    __shared__ double acc[NCLS];
    int c = threadIdx.x;
    if (c < NCLS) {
        double P = 0.0;
        for (int b = 0; b < NBUCK; b++)
            P += (double)(gP[c * NBUCK + b] >> CNT_SHIFT);
        double loss = 0.0, nneg = 0.0, ppos = 0.0, topAvg = -1.0;
        const double esc = 1.0 / 65535.0;
        for (int b = NBUCK - 1; b >= 0; b--) {
            u64 vp = gP[c * NBUCK + b];
            double cp = (double)(vp >> CNT_SHIFT);
            if (cp > 0.0) {
                double sp = (double)(vp & SUM_MASK) * esc;
                loss += sp / (P + nneg);
                ppos += cp;
            }
            u64 vn = gN[c * NBUCK + b];
            double cn = (double)(vn >> CNT_SHIFT);
            if (cn > 0.0) {
                double sn = (double)(vn & SUM_MASK) * esc;
                double avg = sn / cn;
                if (topAvg < 0.0) topAvg = avg;
                double rem = P - ppos;
                if (rem > 0.0)
                    loss += avg * rem * (1.0 / (P + nneg) - 1.0 / (P + nneg + cn));
                nneg += cn;
            }
        }
        if (P == 0.0) loss = (topAvg >= 0.0) ? topAvg : 0.0;
        acc[c] = loss;
    }
    __syncthreads();
    if (threadIdx.x == 0) {
        double tsum = 0.0;
        for (int i = 0; i < NCLS; i++) tsum += acc[i];
        out[0] = (float)(tsum / (double)NCLS);
    }
}

extern "C" void kernel_launch(void* const* d_in, const int* in_sizes, int n_in,
                              void* d_out, int out_size, void* d_ws, size_t ws_size,
                              hipStream_t stream) {
    const float* x = (const float*)d_in[0];
    const int* tgt = (const int*)d_in[1];
    int n = in_sizes[0] / NCLS;

    u64* gP = (u64*)d_ws;                         // [NCLS][NBUCK]
    u64* gN = gP + NCLS * NBUCK;                  // [NCLS][NBUCK]
    size_t histBytes = 2ull * NCLS * NBUCK * sizeof(u64);          // 80 KB
    unsigned short* posE = (unsigned short*)((char*)d_ws + histBytes);
    unsigned short* negT = posE + n;              // [NCLS][n] u16
    size_t needed = histBytes + (size_t)n * 2 + (size_t)NCLS * n * 2;

    hipMemsetAsync(d_ws, 0, histBytes, stream);

    if (ws_size >= needed && (n & 7) == 0) {
        hipLaunchKernelGGL(lv_pass1, dim3(1024), dim3(512), 0, stream,
                           x, tgt, negT, posE, n);
        hipLaunchKernelGGL(lv_hist_neg, dim3(64, NCLS), dim3(512), 0, stream,
                           negT, gN, n);
        hipLaunchKernelGGL(lv_hist_pos, dim3(64), dim3(512), 0, stream,
                           posE, tgt, gP, n);
    } else {
        hipLaunchKernelGGL(lv_hist_fused, dim3(512), dim3(512), 0, stream,
                           x, tgt, gN, gP, n);
    }
    hipLaunchKernelGGL(lovasz_final, dim3(1), dim3(64), 0, stream,
                       gN, gP, (float*)d_out);
}

// Round 3
// 61.955 us; speedup vs baseline: 6.1287x; 2.4919x over previous
//
#include <hip/hip_runtime.h>
#include <stdint.h>

typedef unsigned long long u64;

#define NCLS 20
#define NBUCK 256
#define CNT_SHIFT 44
#define SUM_MASK ((1ull << CNT_SHIFT) - 1ull)

__device__ __forceinline__ unsigned short quant16(float err) {
    float f = err * 65535.0f + 0.5f;
    unsigned q = (unsigned)f;
    return (unsigned short)(q > 65534u ? 65534u : q);  // 0xFFFF reserved as sentinel
}

// ---------------- Pass 1: softmax + quantized-error transpose ----------------
__global__ __launch_bounds__(512) void lv_pass1(
    const float* __restrict__ x, const int* __restrict__ tgt,
    unsigned short* __restrict__ negT, unsigned short* __restrict__ posE, int n)
{
    const int stride = gridDim.x * blockDim.x;
    for (int row = blockIdx.x * blockDim.x + threadIdx.x; row < n; row += stride) {
        const float4* rp = reinterpret_cast<const float4*>(x + (size_t)row * NCLS);
        float4 q0 = rp[0], q1 = rp[1], q2 = rp[2], q3 = rp[3], q4 = rp[4];
        float v[NCLS] = {q0.x,q0.y,q0.z,q0.w, q1.x,q1.y,q1.z,q1.w,
                         q2.x,q2.y,q2.z,q2.w, q3.x,q3.y,q3.z,q3.w,
                         q4.x,q4.y,q4.z,q4.w};
        float m = v[0];
#pragma unroll
        for (int c = 1; c < NCLS; c++) m = fmaxf(m, v[c]);
        float e[NCLS];
        float s = 0.0f;
#pragma unroll
        for (int c = 0; c < NCLS; c++) { e[c] = __expf(v[c] - m); s += e[c]; }
        float inv = 1.0f / s;
        int t = tgt[row];
        unsigned short pq = 0;
#pragma unroll
        for (int c = 0; c < NCLS; c++) {
            float p = e[c] * inv;
            bool pos = (c == t);
            unsigned short q = quant16(pos ? (1.0f - p) : p);
            if (pos) pq = q;
            negT[(size_t)c * n + row] = pos ? (unsigned short)0xFFFFu : q;
        }
        posE[row] = pq;
    }
}

// ---------------- Pass 2a: negatives histogram (one class per blockIdx.y) ---
__global__ __launch_bounds__(512) void lv_hist_neg(
    const unsigned short* __restrict__ negT, u64* __restrict__ gN, int n)
{
    __shared__ u64 sH[8][NBUCK];   // 8 waves x 2KB = 16KB
    for (int i = threadIdx.x; i < 8 * NBUCK; i += blockDim.x) ((u64*)sH)[i] = 0;
    __syncthreads();

    const int wave = threadIdx.x >> 6;
    const int c = blockIdx.y;
    const uint4* base = reinterpret_cast<const uint4*>(negT + (size_t)c * n);
    const int nv = n >> 3;
    const int stride = gridDim.x * blockDim.x;
    for (int i = blockIdx.x * blockDim.x + threadIdx.x; i < nv; i += stride) {
        uint4 w = base[i];
        unsigned vals[8] = {w.x & 0xFFFFu, w.x >> 16, w.y & 0xFFFFu, w.y >> 16,
                            w.z & 0xFFFFu, w.z >> 16, w.w & 0xFFFFu, w.w >> 16};
#pragma unroll
        for (int k = 0; k < 8; k++) {
            unsigned vv = vals[k];
            if (vv != 0xFFFFu)
                atomicAdd(&sH[wave][vv >> 8], (1ull << CNT_SHIFT) | (u64)vv);
        }
    }
    __syncthreads();
    for (int b = threadIdx.x; b < NBUCK; b += blockDim.x) {
        u64 t = 0;
#pragma unroll
        for (int w2 = 0; w2 < 8; w2++) t += sH[w2][b];
        if (t) atomicAdd(&gN[c * NBUCK + b], t);
    }
}

// ---------------- Pass 2b: positives histogram -------------------------------
__global__ __launch_bounds__(512) void lv_hist_pos(
    const unsigned short* __restrict__ posE, const int* __restrict__ tgt,
    u64* __restrict__ gP, int n)
{
    __shared__ u64 sH[NCLS * NBUCK];             // 40KB
    for (int i = threadIdx.x; i < NCLS * NBUCK; i += blockDim.x) sH[i] = 0;
    __syncthreads();
    const int stride = gridDim.x * blockDim.x;
    for (int i = blockIdx.x * blockDim.x + threadIdx.x; i < n; i += stride) {
        unsigned vv = posE[i];
        int t = tgt[i];
        atomicAdd(&sH[t * NBUCK + (vv >> 8)], (1ull << CNT_SHIFT) | (u64)vv);
    }
    __syncthreads();
    for (int i = threadIdx.x; i < NCLS * NBUCK; i += blockDim.x) {
        u64 v = sH[i];
        if (v) atomicAdd(&gP[i], v);
    }
}

// ---------------- Fallback (small ws): fused hist ----------------------------
__global__ __launch_bounds__(512, 2) void lv_hist_fused(
    const float* __restrict__ x, const int* __restrict__ tgt,
    u64* __restrict__ gN, u64* __restrict__ gP, int n)
{
    __shared__ u64 sN[NCLS * (NBUCK + 1)];
    for (int i = threadIdx.x; i < NCLS * (NBUCK + 1); i += blockDim.x) sN[i] = 0;
    __syncthreads();
    const int stride = gridDim.x * blockDim.x;
    for (int row = blockIdx.x * blockDim.x + threadIdx.x; row < n; row += stride) {
        const float4* rp = reinterpret_cast<const float4*>(x + (size_t)row * NCLS);
        float4 q0 = rp[0], q1 = rp[1], q2 = rp[2], q3 = rp[3], q4 = rp[4];
        float v[NCLS] = {q0.x,q0.y,q0.z,q0.w, q1.x,q1.y,q1.z,q1.w,
                         q2.x,q2.y,q2.z,q2.w, q3.x,q3.y,q3.z,q3.w,
                         q4.x,q4.y,q4.z,q4.w};
        float m = v[0];
#pragma unroll
        for (int c = 1; c < NCLS; c++) m = fmaxf(m, v[c]);
        float e[NCLS]; float s = 0.0f;
#pragma unroll
        for (int c = 0; c < NCLS; c++) { e[c] = __expf(v[c] - m); s += e[c]; }
        float inv = 1.0f / s;
        int t = tgt[row];
#pragma unroll
        for (int c = 0; c < NCLS; c++) {
            float p = e[c] * inv;
            bool pos = (c == t);
            unsigned vv = quant16(pos ? (1.0f - p) : p);
            u64 pv = (1ull << CNT_SHIFT) | (u64)vv;
            if (pos) atomicAdd(&gP[c * NBUCK + (vv >> 8)], pv);
            else     atomicAdd(&sN[c * (NBUCK + 1) + (vv >> 8)], pv);
        }
    }
    __syncthreads();
    for (int i = threadIdx.x; i < NCLS * NBUCK; i += blockDim.x) {
        int c = i / NBUCK, b = i - c * NBUCK;
        u64 val = sN[c * (NBUCK + 1) + b];
        if (val) atomicAdd(&gN[i], val);
    }
}

// ---------------- Final: per-class parallel Lovasz walk (scan-based) ---------
// Descending-bucket weights close-form via prefix sums:
//   pos in bucket b:  weight 1/(P + negAbove[b])  (all positives in bucket share it)
//   neg run in b:     (P - posIncl[b]) * [1/(P+negAbove[b]) - 1/(P+negAbove[b]+cn)]
__global__ __launch_bounds__(NBUCK) void lv_final_class(
    const u64* __restrict__ gN, const u64* __restrict__ gP, double* __restrict__ gLoss)
{
    __shared__ double sc[NBUCK];
    __shared__ int smax;
    const int c = blockIdx.x;
    const int b = threadIdx.x;
    const int r = NBUCK - 1 - b;                 // descending rank
    const double esc = 1.0 / 65535.0;

    u64 vp = gP[c * NBUCK + b], vn = gN[c * NBUCK + b];
    double cp = (double)(vp >> CNT_SHIFT), sp = (double)(vp & SUM_MASK) * esc;
    double cn = (double)(vn >> CNT_SHIFT), sn = (double)(vn & SUM_MASK) * esc;

    // scan 1: negatives, descending inclusive (Hillis-Steele over rank r)
    sc[r] = cn; __syncthreads();
#pragma unroll
    for (int off = 1; off < NBUCK; off <<= 1) {
        double t = (r >= off) ? sc[r - off] : 0.0; __syncthreads();
        sc[r] += t; __syncthreads();
    }
    double negAbove = sc[r] - cn;
    __syncthreads();

    // scan 2: positives, descending inclusive
    sc[r] = cp; __syncthreads();
#pragma unroll
    for (int off = 1; off < NBUCK; off <<= 1) {
        double t = (r >= off) ? sc[r - off] : 0.0; __syncthreads();
        sc[r] += t; __syncthreads();
    }
    double posIncl = sc[r];
    double P = sc[NBUCK - 1];                    // total positives
    __syncthreads();

    double contrib = 0.0;
    double denom0 = P + negAbove;
    if (cp > 0.0) contrib += sp / denom0;
    double rem = P - posIncl;
    if (cn > 0.0 && rem > 0.0)
        contrib += (sn / cn) * rem * (1.0 / denom0 - 1.0 / (denom0 + cn));

    // block reduce
    sc[b] = contrib; __syncthreads();
#pragma unroll
    for (int off = NBUCK / 2; off > 0; off >>= 1) {
        if (b < off) sc[b] += sc[b + off];
        __syncthreads();
    }

    if (P > 0.0) {
        if (b == 0) gLoss[c] = sc[0];
    } else {
        // degenerate: loss = err of top nonempty bucket (approx by bucket avg)
        if (b == 0) smax = -1;
        __syncthreads();
        if (cn > 0.0) atomicMax(&smax, b);
        __syncthreads();
        if (smax >= 0) { if (b == smax) gLoss[c] = sn / cn; }
        else if (b == 0) gLoss[c] = 0.0;
    }
}

__global__ void lv_mean(const double* __restrict__ gLoss, float* __restrict__ out)
{
    if (threadIdx.x == 0) {
        double s = 0.0;
        for (int i = 0; i < NCLS; i++) s += gLoss[i];
        out[0] = (float)(s / (double)NCLS);
    }
}

extern "C" void kernel_launch(void* const* d_in, const int* in_sizes, int n_in,
                              void* d_out, int out_size, void* d_ws, size_t ws_size,
                              hipStream_t stream) {
    const float* x = (const float*)d_in[0];
    const int* tgt = (const int*)d_in[1];
    int n = in_sizes[0] / NCLS;

    u64* gP = (u64*)d_ws;                         // [NCLS][NBUCK]
    u64* gN = gP + NCLS * NBUCK;                  // [NCLS][NBUCK]
    size_t histBytes = 2ull * NCLS * NBUCK * sizeof(u64);          // 80 KB
    double* gLoss = (double*)((char*)d_ws + histBytes);            // [NCLS]
    size_t headBytes = histBytes + NCLS * sizeof(double);
    unsigned short* posE = (unsigned short*)((char*)d_ws + headBytes);
    unsigned short* negT = posE + n;              // [NCLS][n] u16
    size_t needed = headBytes + (size_t)n * 2 + (size_t)NCLS * n * 2;

    hipMemsetAsync(d_ws, 0, histBytes, stream);

    if (ws_size >= needed && (n & 7) == 0) {
        hipLaunchKernelGGL(lv_pass1, dim3(1024), dim3(512), 0, stream,
                           x, tgt, negT, posE, n);
        hipLaunchKernelGGL(lv_hist_neg, dim3(64, NCLS), dim3(512), 0, stream,
                           negT, gN, n);
        hipLaunchKernelGGL(lv_hist_pos, dim3(64), dim3(512), 0, stream,
                           posE, tgt, gP, n);
    } else {
        hipLaunchKernelGGL(lv_hist_fused, dim3(512), dim3(512), 0, stream,
                           x, tgt, gN, gP, n);
    }
    hipLaunchKernelGGL(lv_final_class, dim3(NCLS), dim3(NBUCK), 0, stream,
                       gN, gP, gLoss);
    hipLaunchKernelGGL(lv_mean, dim3(1), dim3(64), 0, stream,
                       gLoss, (float*)d_out);
}

// Round 4
// 46.679 us; speedup vs baseline: 8.1343x; 1.3272x over previous
//
#include <hip/hip_runtime.h>
#include <stdint.h>

typedef unsigned int u32;
typedef unsigned long long u64;

#define NCLS 20
#define NBUCK 256

// q = round(err * 254), q in [0,254]; 255 reserved as positive-slot sentinel.
// Dequant value = q / 254. Max per-item quantization error = 1/508.
__device__ __forceinline__ u32 quant8(float err) {
    float f = fmaf(err, 254.0f, 0.5f);
    u32 q = (u32)f;
    return q > 254u ? 254u : q;
}

// ---------------- Pass 1: softmax + 8-bit error quantization ----------------
// 2 rows per thread; negT[c][row] bytes written as packed u16 (2 rows).
// Blocks 0..9 also zero the 40KB gP/gN histogram region (runs before hist
// kernels by stream order).
__global__ __launch_bounds__(512) void lv_pass1(
    const float* __restrict__ x, const int* __restrict__ tgt,
    unsigned char* __restrict__ negT, unsigned char* __restrict__ posE,
    u64* __restrict__ zeroRegion, int n)
{
    {
        int z = blockIdx.x * 512 + threadIdx.x;
        if (z < (2 * NCLS * NBUCK * 4) / 8) zeroRegion[z] = 0;  // 5120 u64 = 40KB
    }
    const int npair = n >> 1;
    const int stride = gridDim.x * blockDim.x;
    for (int i = blockIdx.x * blockDim.x + threadIdx.x; i < npair; i += stride) {
        const float4* rp = reinterpret_cast<const float4*>(x + (size_t)i * (2 * NCLS));
        float4 a0 = rp[0], a1 = rp[1], a2 = rp[2], a3 = rp[3], a4 = rp[4];
        float4 b0 = rp[5], b1 = rp[6], b2 = rp[7], b3 = rp[8], b4 = rp[9];
        float va[NCLS] = {a0.x,a0.y,a0.z,a0.w, a1.x,a1.y,a1.z,a1.w,
                          a2.x,a2.y,a2.z,a2.w, a3.x,a3.y,a3.z,a3.w,
                          a4.x,a4.y,a4.z,a4.w};
        float vb[NCLS] = {b0.x,b0.y,b0.z,b0.w, b1.x,b1.y,b1.z,b1.w,
                          b2.x,b2.y,b2.z,b2.w, b3.x,b3.y,b3.z,b3.w,
                          b4.x,b4.y,b4.z,b4.w};
        float ma = va[0], mb = vb[0];
#pragma unroll
        for (int c = 1; c < NCLS; c++) { ma = fmaxf(ma, va[c]); mb = fmaxf(mb, vb[c]); }
        float sa = 0.0f, sb = 0.0f;
#pragma unroll
        for (int c = 0; c < NCLS; c++) {
            va[c] = __expf(va[c] - ma); sa += va[c];
            vb[c] = __expf(vb[c] - mb); sb += vb[c];
        }
        float ia = 1.0f / sa, ib = 1.0f / sb;
        int2 tt = *reinterpret_cast<const int2*>(tgt + 2 * i);
        int t0 = tt.x, t1 = tt.y;
        u32 pq0 = 0, pq1 = 0;
#pragma unroll
        for (int c = 0; c < NCLS; c++) {
            float p0 = va[c] * ia, p1 = vb[c] * ib;
            u32 q0 = quant8((c == t0) ? (1.0f - p0) : p0);
            u32 q1 = quant8((c == t1) ? (1.0f - p1) : p1);
            if (c == t0) { pq0 = q0; q0 = 255u; }
            if (c == t1) { pq1 = q1; q1 = 255u; }
            reinterpret_cast<unsigned short*>(negT + (size_t)c * n)[i] =
                (unsigned short)(q0 | (q1 << 8));
        }
        reinterpret_cast<unsigned short*>(posE)[i] = (unsigned short)(pq0 | (pq1 << 8));
    }
}

// ---------------- Pass 2a: negatives count histogram (class = blockIdx.y) ---
__global__ __launch_bounds__(512) void lv_hist_neg(
    const unsigned char* __restrict__ negT, u32* __restrict__ gN, int n)
{
    __shared__ u32 sH[8][NBUCK];                  // 8 waves x 1KB
    for (int i = threadIdx.x; i < 8 * NBUCK; i += blockDim.x) (&sH[0][0])[i] = 0;
    __syncthreads();
    const int wave = threadIdx.x >> 6;
    const int c = blockIdx.y;
    const uint4* base = reinterpret_cast<const uint4*>(negT + (size_t)c * n);
    const int nv = n >> 4;
    const int stride = gridDim.x * blockDim.x;
    for (int i = blockIdx.x * blockDim.x + threadIdx.x; i < nv; i += stride) {
        uint4 w = base[i];
        u32 wd[4] = {w.x, w.y, w.z, w.w};
#pragma unroll
        for (int j = 0; j < 4; j++) {
#pragma unroll
            for (int k = 0; k < 4; k++) {
                u32 b = (wd[j] >> (8 * k)) & 0xFFu;
                if (b != 255u) atomicAdd(&sH[wave][b], 1u);
            }
        }
    }
    __syncthreads();
    for (int b = threadIdx.x; b < NBUCK; b += blockDim.x) {
        u32 t = sH[0][b] + sH[1][b] + sH[2][b] + sH[3][b]
              + sH[4][b] + sH[5][b] + sH[6][b] + sH[7][b];
        if (t) atomicAdd(&gN[c * NBUCK + b], t);
    }
}

// ---------------- Pass 2b: positives count histogram -------------------------
__global__ __launch_bounds__(512) void lv_hist_pos(
    const unsigned char* __restrict__ posE, const int* __restrict__ tgt,
    u32* __restrict__ gP, int n)
{
    __shared__ u32 sH[NCLS * NBUCK];              // 20KB
    for (int i = threadIdx.x; i < NCLS * NBUCK; i += blockDim.x) sH[i] = 0;
    __syncthreads();
    const uint4* pb = reinterpret_cast<const uint4*>(posE);
    const int4* tb = reinterpret_cast<const int4*>(tgt);
    const int nv = n >> 4;
    const int stride = gridDim.x * blockDim.x;
    for (int i = blockIdx.x * blockDim.x + threadIdx.x; i < nv; i += stride) {
        uint4 w = pb[i];
        u32 wd[4] = {w.x, w.y, w.z, w.w};
#pragma unroll
        for (int j = 0; j < 4; j++) {
            int4 t4 = tb[i * 4 + j];
            int ts[4] = {t4.x, t4.y, t4.z, t4.w};
#pragma unroll
            for (int k = 0; k < 4; k++) {
                u32 q = (wd[j] >> (8 * k)) & 0xFFu;
                atomicAdd(&sH[ts[k] * NBUCK + q], 1u);
            }
        }
    }
    __syncthreads();
    for (int i = threadIdx.x; i < NCLS * NBUCK; i += blockDim.x) {
        u32 v = sH[i];
        if (v) atomicAdd(&gP[i], v);
    }
}

// ---------------- Fallback (small ws): fused count hist ----------------------
__global__ __launch_bounds__(512) void lv_hist_fused(
    const float* __restrict__ x, const int* __restrict__ tgt,
    u32* __restrict__ gN, u32* __restrict__ gP, int n)
{
    __shared__ u32 sN[NCLS * NBUCK];
    __shared__ u32 sP[NCLS * NBUCK];
    for (int i = threadIdx.x; i < NCLS * NBUCK; i += blockDim.x) { sN[i] = 0; sP[i] = 0; }
    __syncthreads();
    const int stride = gridDim.x * blockDim.x;
    for (int row = blockIdx.x * blockDim.x + threadIdx.x; row < n; row += stride) {
        const float4* rp = reinterpret_cast<const float4*>(x + (size_t)row * NCLS);
        float4 q0 = rp[0], q1 = rp[1], q2 = rp[2], q3 = rp[3], q4 = rp[4];
        float v[NCLS] = {q0.x,q0.y,q0.z,q0.w, q1.x,q1.y,q1.z,q1.w,
                         q2.x,q2.y,q2.z,q2.w, q3.x,q3.y,q3.z,q3.w,
                         q4.x,q4.y,q4.z,q4.w};
        float m = v[0];
#pragma unroll
        for (int c = 1; c < NCLS; c++) m = fmaxf(m, v[c]);
        float s = 0.0f;
#pragma unroll
        for (int c = 0; c < NCLS; c++) { v[c] = __expf(v[c] - m); s += v[c]; }
        float inv = 1.0f / s;
        int t = tgt[row];
#pragma unroll
        for (int c = 0; c < NCLS; c++) {
            float p = v[c] * inv;
            bool pos = (c == t);
            u32 q = quant8(pos ? (1.0f - p) : p);
            if (pos) atomicAdd(&sP[c * NBUCK + q], 1u);
            else     atomicAdd(&sN[c * NBUCK + q], 1u);
        }
    }
    __syncthreads();
    for (int i = threadIdx.x; i < NCLS * NBUCK; i += blockDim.x) {
        if (sN[i]) atomicAdd(&gN[i], sN[i]);
        if (sP[i]) atomicAdd(&gP[i], sP[i]);
    }
}

// ---------------- Final: per-class parallel Lovasz walk ----------------------
// Bucket value = b/254. Closed form per bucket via descending prefix sums:
//   positives: cnt*val / (P + negAbove)
//   negatives: val * (P - posIncl) * [1/(P+negAbove) - 1/(P+negAbove+cn)]
__global__ __launch_bounds__(NBUCK) void lv_final_class(
    const u32* __restrict__ gN, const u32* __restrict__ gP, double* __restrict__ gLoss)
{
    __shared__ double sc[NBUCK];
    __shared__ int smax;
    const int c = blockIdx.x;
    const int b = threadIdx.x;
    const int r = NBUCK - 1 - b;                  // descending rank
    double cp = (double)gP[c * NBUCK + b];
    double cn = (double)gN[c * NBUCK + b];
    double val = (double)b * (1.0 / 254.0);

    sc[r] = cn; __syncthreads();
#pragma unroll
    for (int off = 1; off < NBUCK; off <<= 1) {
        double t = (r >= off) ? sc[r - off] : 0.0; __syncthreads();
        sc[r] += t; __syncthreads();
    }
    double negAbove = sc[r] - cn;
    __syncthreads();

    sc[r] = cp; __syncthreads();
#pragma unroll
    for (int off = 1; off < NBUCK; off <<= 1) {
        double t = (r >= off) ? sc[r - off] : 0.0; __syncthreads();
        sc[r] += t; __syncthreads();
    }
    double posIncl = sc[r];
    double P = sc[NBUCK - 1];
    __syncthreads();

    double contrib = 0.0;
    double denom0 = P + negAbove;
    if (cp > 0.0) contrib += cp * val / denom0;
    double rem = P - posIncl;
    if (cn > 0.0 && rem > 0.0)
        contrib += val * rem * (1.0 / denom0 - 1.0 / (denom0 + cn));

    sc[b] = contrib; __syncthreads();
#pragma unroll
    for (int off = NBUCK / 2; off > 0; off >>= 1) {
        if (b < off) sc[b] += sc[b + off];
        __syncthreads();
    }

    if (P > 0.0) {
        if (b == 0) gLoss[c] = sc[0];
    } else {
        if (b == 0) smax = -1;
        __syncthreads();
        if (cn > 0.0) atomicMax(&smax, b);
        __syncthreads();
        if (smax >= 0) { if (b == smax) gLoss[c] = val; }
        else if (b == 0) gLoss[c] = 0.0;
    }
}

__global__ void lv_mean(const double* __restrict__ gLoss, float* __restrict__ out)
{
    if (threadIdx.x == 0) {
        double s = 0.0;
        for (int i = 0; i < NCLS; i++) s += gLoss[i];
        out[0] = (float)(s / (double)NCLS);
    }
}

extern "C" void kernel_launch(void* const* d_in, const int* in_sizes, int n_in,
                              void* d_out, int out_size, void* d_ws, size_t ws_size,
                              hipStream_t stream) {
    const float* x = (const float*)d_in[0];
    const int* tgt = (const int*)d_in[1];
    int n = in_sizes[0] / NCLS;

    u32* gP = (u32*)d_ws;                          // [NCLS][NBUCK] u32
    u32* gN = gP + NCLS * NBUCK;                   // [NCLS][NBUCK] u32
    size_t histBytes = 2ull * NCLS * NBUCK * sizeof(u32);          // 40KB
    double* gLoss = (double*)((char*)d_ws + histBytes);            // [NCLS]
    size_t headBytes = histBytes + NCLS * sizeof(double);          // 41120 (16B-mult)
    unsigned char* posE = (unsigned char*)((char*)d_ws + headBytes);
    unsigned char* negT = posE + n;                // [NCLS][n] u8
    size_t needed = headBytes + (size_t)n + (size_t)NCLS * n;

    if (ws_size >= needed && (n & 15) == 0) {
        hipLaunchKernelGGL(lv_pass1, dim3(1024), dim3(512), 0, stream,
                           x, tgt, negT, posE, (u64*)d_ws, n);
        hipLaunchKernelGGL(lv_hist_neg, dim3(32, NCLS), dim3(512), 0, stream,
                           negT, gN, n);
        hipLaunchKernelGGL(lv_hist_pos, dim3(64), dim3(512), 0, stream,
                           posE, tgt, gP, n);
    } else {
        hipMemsetAsync(d_ws, 0, histBytes, stream);
        hipLaunchKernelGGL(lv_hist_fused, dim3(512), dim3(512), 0, stream,
                           x, tgt, gN, gP, n);
    }
    hipLaunchKernelGGL(lv_final_class, dim3(NCLS), dim3(NBUCK), 0, stream,
                       gN, gP, gLoss);
    hipLaunchKernelGGL(lv_mean, dim3(1), dim3(64), 0, stream,
                       gLoss, (float*)d_out);
}